// Round 1
// baseline (255.090 us; speedup 1.0000x reference)
//
#include <hip/hip_runtime.h>
#include <stdint.h>

// SimCLR clear loss, MI355X — round 5: overhead attack.
//  - logdenom fused into gemm via completion counter (saves 1 launch)
//  - grid 1536 (= 6 blocks/CU exactly one residency round); pos-fold on
//    blocks [1408,1536): tile-free (nT~1330) AND first-round co-resident
//  - plan label histogram loads vectorized int4

#define NROWS 8192
#define DIM   512
#define NCLS  7
#define GEMM_GRID 1536
#define POSB0 1408        // blocks [POSB0, GEMM_GRID) also compute pos partials

typedef _Float16 f16x8 __attribute__((ext_vector_type(8)));
typedef _Float16 f16x4 __attribute__((ext_vector_type(4)));
typedef float    f32x4 __attribute__((ext_vector_type(4)));

__device__ __forceinline__ void load16_g2l(void* lds, const void* g) {
    auto* l3 = reinterpret_cast<__attribute__((address_space(3))) uint32_t*>(
        reinterpret_cast<uintptr_t>(lds));
    auto* g1 = reinterpret_cast<const __attribute__((address_space(1))) uint32_t*>(
        reinterpret_cast<uintptr_t>(g));
    __builtin_amdgcn_global_load_lds(g1, l3, 16, 0, 0);
}

// ---------------- 1. planner ----------------
// Per-64-row-segment class counts -> wavebase[128][7] (exclusive prefix + class
// offset), class offsets, triangular 64-tile table, denom/loss/counter zero.
__global__ __launch_bounds__(256) void plan_kernel(const int* __restrict__ labels,
                                                   int* __restrict__ wavebase,
                                                   int4* __restrict__ tiles,
                                                   int* __restrict__ nTiles,
                                                   float* __restrict__ denomS,
                                                   float* __restrict__ loss) {
    __shared__ int cnt[128][NCLS];
    __shared__ int pref[128][NCLS];
    __shared__ int hist[NCLS];
    __shared__ int off[NCLS + 1];
    __shared__ int tb[NCLS + 1];
    const int tid = threadIdx.x;

    if (tid < 128) {
        int c0 = 0, c1 = 0, c2 = 0, c3 = 0, c4 = 0, c5 = 0, c6 = 0;
        const int4* l4 = (const int4*)labels + tid * 16;   // 64 labels = 16 int4
        #pragma unroll 4
        for (int j = 0; j < 16; ++j) {
            int4 v = l4[j];
            c0 += (v.x == 0) + (v.y == 0) + (v.z == 0) + (v.w == 0);
            c1 += (v.x == 1) + (v.y == 1) + (v.z == 1) + (v.w == 1);
            c2 += (v.x == 2) + (v.y == 2) + (v.z == 2) + (v.w == 2);
            c3 += (v.x == 3) + (v.y == 3) + (v.z == 3) + (v.w == 3);
            c4 += (v.x == 4) + (v.y == 4) + (v.z == 4) + (v.w == 4);
            c5 += (v.x == 5) + (v.y == 5) + (v.z == 5) + (v.w == 5);
            c6 += (v.x == 6) + (v.y == 6) + (v.z == 6) + (v.w == 6);
        }
        cnt[tid][0] = c0; cnt[tid][1] = c1; cnt[tid][2] = c2; cnt[tid][3] = c3;
        cnt[tid][4] = c4; cnt[tid][5] = c5; cnt[tid][6] = c6;
    }
    __syncthreads();
    if (tid < NCLS) {
        int run = 0;
        for (int s = 0; s < 128; ++s) { pref[s][tid] = run; run += cnt[s][tid]; }
        hist[tid] = run;
    }
    __syncthreads();
    if (tid == 0) {
        int o = 0, t = 0;
        for (int c = 0; c < NCLS; ++c) {
            off[c] = o; tb[c] = t;
            int T = (hist[c] + 63) >> 6;
            o += hist[c]; t += T * (T + 1) / 2;
        }
        off[NCLS] = o; tb[NCLS] = t;
        nTiles[0] = t;
        nTiles[1] = 0;     // completion counter for fused logdenom
        *loss = 0.f;
    }
    __syncthreads();
    for (int i = tid; i < 128 * NCLS; i += 256) {
        int s = i / NCLS, c = i - s * NCLS;
        wavebase[i] = off[c] + pref[s][c];
    }
    const int tot = tb[NCLS];
    for (int t = tid; t < tot; t += 256) {
        int c = 0;
        while (t >= tb[c + 1]) ++c;
        int rem = t - tb[c];
        int T = (hist[c] + 63) >> 6;
        int ti = 0;
        while (rem >= T - ti) { rem -= (T - ti); ++ti; }   // ti<=tj
        int tj = ti + rem;
        tiles[t] = make_int4(off[c] + ti * 64, off[c] + tj * 64, off[c] + hist[c], 0);
    }
    for (int i = tid; i < NROWS; i += 256) denomS[i] = 0.f;
}

// ---------------- 2. fused scatter + fp32->f16 cast (atomic-free) ----------------
// Wave handles one row; in-segment rank via ballot, dest = wavebase + rank.
__global__ __launch_bounds__(256) void scatter_cast_kernel(const float* __restrict__ x,
                                                           const int* __restrict__ labels,
                                                           const int* __restrict__ wavebase,
                                                           _Float16* __restrict__ y) {
    const int wv   = threadIdx.x >> 6;
    const int lane = threadIdx.x & 63;
    const int row  = blockIdx.x * 4 + wv;        // 0..8191
    const int seg  = row >> 6;
    const int lab  = labels[seg * 64 + lane];    // label of segment-row `lane`
    unsigned long long m0 = __ballot(lab == 0), m1 = __ballot(lab == 1),
                       m2 = __ballot(lab == 2), m3 = __ballot(lab == 3),
                       m4 = __ballot(lab == 4), m5 = __ballot(lab == 5),
                       m6 = __ballot(lab == 6);
    unsigned long long mymask =
        lab == 0 ? m0 : lab == 1 ? m1 : lab == 2 ? m2 : lab == 3 ? m3 :
        lab == 4 ? m4 : lab == 5 ? m5 : m6;
    const unsigned long long lt = (1ull << lane) - 1ull;
    int dest_lane = wavebase[seg * NCLS + lab] + __builtin_popcountll(mymask & lt);
    int dest = __shfl(dest_lane, row & 63, 64);  // dest of THIS wave's row

    const float4* src = (const float4*)(x + (size_t)row * DIM);
    _Float16* dst = y + (size_t)dest * DIM;
    #pragma unroll
    for (int p = 0; p < 2; ++p) {
        float4 v = src[lane + p * 64];
        f16x4 h;
        h[0] = (_Float16)v.x; h[1] = (_Float16)v.y;
        h[2] = (_Float16)v.z; h[3] = (_Float16)v.w;
        *(f16x4*)(dst + (lane + p * 64) * 4) = h;
    }
}

// ---------------- 3. fused GEMM over upper-triangle 64x64 class tiles + pos + log ----------------
// 4 waves, each a 32x32 quadrant (acc 2x2 of f32x4). LDS fragment-ordered
// [2][4][64][8]; off-diag tiles emit row-sums AND col-sums (S^T reuse);
// diag tiles stage A only and mask i!=j. Last block (completion counter)
// computes mean(log(denom)) — replaces the former 4th kernel.
__global__ __launch_bounds__(256, 6) void gemm_denom_kernel(const _Float16* __restrict__ X,
                                                            const int4* __restrict__ tiles,
                                                            int* __restrict__ nTiles,
                                                            float* __restrict__ denom,
                                                            const float* __restrict__ o1,
                                                            const float* __restrict__ o2,
                                                            float* __restrict__ loss) {
    __shared__ __align__(16) _Float16 Atile[4096];  // [2][4][64][8] = 8 KiB
    __shared__ __align__(16) _Float16 Btile[4096];

    const int tid  = threadIdx.x;
    const int lane = tid & 63;
    const int wv   = tid >> 6;
    const int lc   = lane & 15;
    const int lq   = lane >> 4;
    const int l8   = lq * 8;
    const int nT   = nTiles[0];

    for (int t = blockIdx.x; t < nT; t += gridDim.x) {
        const int4 d = tiles[t];
        const int bm = d.x, bn = d.y, end = d.z;
        const bool diag = (bm == bn);

        f32x4 acc[2][2] = {};

        for (int kb = 0; kb < DIM; kb += 64) {
            __syncthreads();
            #pragma unroll
            for (int g = 0; g < 4; ++g) {
                int grp = wv + g * 4;             // 0..15, wave-uniform
                if (diag && grp >= 8) continue;   // diag: A tile only
                int idx = grp & 7;
                int kk2 = idx >> 2;
                int rg  = idx & 3;
                int row = (grp < 8 ? bm : bn) + rg * 16 + lc;
                row = min(row, end - 1);          // partial: dup last row, masked later
                int kcol = kb + kk2 * 32 + l8;
                const _Float16* src = X + (size_t)row * DIM + kcol;
                _Float16* dst = (grp < 8 ? Atile : Btile) + ((kk2 * 4 + rg) * 64 + lane) * 8;
                load16_g2l(dst, src);
            }
            __syncthreads();

            const _Float16* Bbase = diag ? Atile : Btile;
            const int rga = (wv >> 1) * 2;
            const int rgb = (wv & 1) * 2;
            #pragma unroll
            for (int kk2 = 0; kk2 < 2; ++kk2) {
                f16x8 af[2], bf[2];
                #pragma unroll
                for (int q = 0; q < 2; ++q)
                    af[q] = *(const f16x8*)&Atile[((kk2 * 4 + rga + q) * 64 + lane) * 8];
                #pragma unroll
                for (int q = 0; q < 2; ++q)
                    bf[q] = *(const f16x8*)&Bbase[((kk2 * 4 + rgb + q) * 64 + lane) * 8];
                #pragma unroll
                for (int mt = 0; mt < 2; ++mt)
                    #pragma unroll
                    for (int nt = 0; nt < 2; ++nt)
                        acc[mt][nt] = __builtin_amdgcn_mfma_f32_16x16x32_f16(
                            af[mt], bf[nt], acc[mt][nt], 0, 0, 0);
            }
        }

        // epilogue. C/D: col = lane&15, row = (lane>>4)*4 + reg   [m89/m91]
        const int row0 = bm + (wv >> 1) * 32;
        const int col0 = bn + (wv & 1) * 32;
        const float cs = 2.0f * 1.4426950408889634f;  // (1/T)*log2(e)

        float colsum[2] = {0.f, 0.f};
        #pragma unroll
        for (int mt = 0; mt < 2; ++mt) {
            #pragma unroll
            for (int r = 0; r < 4; ++r) {
                int grow = row0 + mt * 16 + lq * 4 + r;
                float s = 0.f;
                #pragma unroll
                for (int nt = 0; nt < 2; ++nt) {
                    int gcol = col0 + nt * 16 + lc;
                    float e = exp2f(acc[mt][nt][r] * cs);
                    bool ok = (gcol < end) && (!diag || (grow != gcol));
                    e = ok ? e : 0.f;
                    s += e;
                    colsum[nt] += e;
                }
                #pragma unroll
                for (int dd = 1; dd < 16; dd <<= 1) s += __shfl_xor(s, dd, 64);
                if (lc == 0 && grow < end) atomicAdd(&denom[grow], s);
            }
        }
        if (!diag) {  // mirrored tile's row-sums (row blocks of off-diag are always full)
            #pragma unroll
            for (int nt = 0; nt < 2; ++nt) {
                float c2 = colsum[nt];
                c2 += __shfl_xor(c2, 16, 64);
                c2 += __shfl_xor(c2, 32, 64);
                int gcol = col0 + nt * 16 + lc;
                if (lq == 0 && gcol < end) atomicAdd(&denom[gcol], c2);
            }
        }
    }

    // ---- pos fold on blocks [POSB0, GEMM_GRID): tile-free & first-round resident ----
    if (blockIdx.x >= POSB0) {
        const int wave = (blockIdx.x - POSB0) * 4 + wv;  // 0..511
        float s = 0.f;
        for (int r = wave; r < 4096; r += 512) {
            const float4* a = (const float4*)(o1 + (size_t)r * DIM);
            const float4* b = (const float4*)(o2 + (size_t)r * DIM);
            float4 va = a[lane], vb = b[lane];
            s += va.x * vb.x + va.y * vb.y + va.z * vb.z + va.w * vb.w;
            va = a[lane + 64]; vb = b[lane + 64];
            s += va.x * vb.x + va.y * vb.y + va.z * vb.z + va.w * vb.w;
        }
        #pragma unroll
        for (int dd = 1; dd < 64; dd <<= 1) s += __shfl_xor(s, dd, 64);
        __shared__ float redp[4];
        if (lane == 0) redp[wv] = s;
        __syncthreads();
        if (tid == 0)
            atomicAdd(loss, -(redp[0] + redp[1] + redp[2] + redp[3]) * (1.0f / 2048.0f));
    }

    // ---- completion counter: last block computes mean(log(denom)) ----
    __threadfence();                       // denom/loss atomics visible device-wide
    __shared__ int lastFlag;
    if (tid == 0)
        lastFlag = (atomicAdd(&nTiles[1], 1) == (int)gridDim.x - 1);
    __syncthreads();
    if (lastFlag) {
        __threadfence();                   // acquire: see all blocks' denom atomics
        float v = 0.f;
        const float4* d4 = (const float4*)denom;
        for (int i = tid; i < NROWS / 4; i += 256) {
            float4 q = d4[i];
            v += __logf(q.x) + __logf(q.y) + __logf(q.z) + __logf(q.w);
        }
        v *= (1.0f / 8192.0f);
        #pragma unroll
        for (int dd = 1; dd < 64; dd <<= 1) v += __shfl_xor(v, dd, 64);
        __shared__ float redl[4];
        if ((tid & 63) == 0) redl[tid >> 6] = v;
        __syncthreads();
        if (tid == 0) atomicAdd(loss, redl[0] + redl[1] + redl[2] + redl[3]);
    }
}

extern "C" void kernel_launch(void* const* d_in, const int* in_sizes, int n_in,
                              void* d_out, int out_size, void* d_ws, size_t ws_size,
                              hipStream_t stream) {
    const float* out_full = (const float*)d_in[0];  // [8192, 512]
    const float* out_1    = (const float*)d_in[1];  // [4096, 512]
    const float* out_2    = (const float*)d_in[2];  // [4096, 512]
    const int*   labels   = (const int*)d_in[3];    // [8192]
    float* loss = (float*)d_out;

    char* ws = (char*)d_ws;
    _Float16* Xs       = (_Float16*)ws;                    // 8 MiB
    float*    denomS   = (float*)(ws + 8388608);           // 32 KiB
    int*      wavebase = (int*)(ws + 8421376);             // 3.5 KiB
    int*      nTiles   = (int*)(ws + 8425472);             // [0]=nTiles, [1]=counter
    int4*     tiles    = (int4*)(ws + 8425536);            // <=129 KiB (worst case)

    plan_kernel<<<1, 256, 0, stream>>>(labels, wavebase, tiles, nTiles, denomS, loss);
    scatter_cast_kernel<<<NROWS / 4, 256, 0, stream>>>(out_full, labels, wavebase, Xs);

    gemm_denom_kernel<<<GEMM_GRID, 256, 0, stream>>>(Xs, tiles, nTiles, denomS,
                                                     out_1, out_2, loss);
}

// Round 3
// 141.750 us; speedup vs baseline: 1.7996x; 1.7996x over previous
//
#include <hip/hip_runtime.h>
#include <stdint.h>

// SimCLR clear loss, MI355X — round 7 (= round 6 + grid-size bugfix):
//  - REVERT round-5 fence fusion: per-wave __threadfence() => buffer_wbl2 sc1
//    storm (6144 L2 writebacks) was +130us. Kernel boundary is the cheap fence.
//  - pos-fold lives in scatter at zero extra HBM traffic: block b handles
//    rows {2b, 2b+1, 2b+4096, 2b+4097}; waves 2,3 exchange rows via LDS,
//    waves 0,1 compute the o1.o2 dots. gemm loses pos + o1/o2 reads entirely.
//  - BUGFIX vs round 6: scatter grid is NROWS/4 = 2048 (4 rows per block);
//    the round-6 NROWS/2 launch read rows past 8191 (OOB) and double-added pos.

#define NROWS 8192
#define DIM   512
#define NCLS  7
#define GEMM_GRID 1536

typedef _Float16 f16x8 __attribute__((ext_vector_type(8)));
typedef _Float16 f16x4 __attribute__((ext_vector_type(4)));
typedef float    f32x4 __attribute__((ext_vector_type(4)));

__device__ __forceinline__ void load16_g2l(void* lds, const void* g) {
    auto* l3 = reinterpret_cast<__attribute__((address_space(3))) uint32_t*>(
        reinterpret_cast<uintptr_t>(lds));
    auto* g1 = reinterpret_cast<const __attribute__((address_space(1))) uint32_t*>(
        reinterpret_cast<uintptr_t>(g));
    __builtin_amdgcn_global_load_lds(g1, l3, 16, 0, 0);
}

// ---------------- 1. planner ----------------
__global__ __launch_bounds__(256) void plan_kernel(const int* __restrict__ labels,
                                                   int* __restrict__ wavebase,
                                                   int4* __restrict__ tiles,
                                                   int* __restrict__ nTiles,
                                                   float* __restrict__ denomS,
                                                   float* __restrict__ loss) {
    __shared__ int cnt[128][NCLS];
    __shared__ int pref[128][NCLS];
    __shared__ int hist[NCLS];
    __shared__ int off[NCLS + 1];
    __shared__ int tb[NCLS + 1];
    const int tid = threadIdx.x;

    if (tid < 128) {
        int c0 = 0, c1 = 0, c2 = 0, c3 = 0, c4 = 0, c5 = 0, c6 = 0;
        const int4* l4 = (const int4*)labels + tid * 16;   // 64 labels = 16 int4
        #pragma unroll 4
        for (int j = 0; j < 16; ++j) {
            int4 v = l4[j];
            c0 += (v.x == 0) + (v.y == 0) + (v.z == 0) + (v.w == 0);
            c1 += (v.x == 1) + (v.y == 1) + (v.z == 1) + (v.w == 1);
            c2 += (v.x == 2) + (v.y == 2) + (v.z == 2) + (v.w == 2);
            c3 += (v.x == 3) + (v.y == 3) + (v.z == 3) + (v.w == 3);
            c4 += (v.x == 4) + (v.y == 4) + (v.z == 4) + (v.w == 4);
            c5 += (v.x == 5) + (v.y == 5) + (v.z == 5) + (v.w == 5);
            c6 += (v.x == 6) + (v.y == 6) + (v.z == 6) + (v.w == 6);
        }
        cnt[tid][0] = c0; cnt[tid][1] = c1; cnt[tid][2] = c2; cnt[tid][3] = c3;
        cnt[tid][4] = c4; cnt[tid][5] = c5; cnt[tid][6] = c6;
    }
    __syncthreads();
    if (tid < NCLS) {
        int run = 0;
        for (int s = 0; s < 128; ++s) { pref[s][tid] = run; run += cnt[s][tid]; }
        hist[tid] = run;
    }
    __syncthreads();
    if (tid == 0) {
        int o = 0, t = 0;
        for (int c = 0; c < NCLS; ++c) {
            off[c] = o; tb[c] = t;
            int T = (hist[c] + 63) >> 6;
            o += hist[c]; t += T * (T + 1) / 2;
        }
        off[NCLS] = o; tb[NCLS] = t;
        nTiles[0] = t;
        *loss = 0.f;
    }
    __syncthreads();
    for (int i = tid; i < 128 * NCLS; i += 256) {
        int s = i / NCLS, c = i - s * NCLS;
        wavebase[i] = off[c] + pref[s][c];
    }
    const int tot = tb[NCLS];
    for (int t = tid; t < tot; t += 256) {
        int c = 0;
        while (t >= tb[c + 1]) ++c;
        int rem = t - tb[c];
        int T = (hist[c] + 63) >> 6;
        int ti = 0;
        while (rem >= T - ti) { rem -= (T - ti); ++ti; }   // ti<=tj
        int tj = ti + rem;
        tiles[t] = make_int4(off[c] + ti * 64, off[c] + tj * 64, off[c] + hist[c], 0);
    }
    for (int i = tid; i < NROWS; i += 256) denomS[i] = 0.f;
}

// ---------------- 2. fused scatter + cast + pos dot (atomic-free scatter) ----------------
// Block b (of 2048): waves 0,1 -> rows 2b,2b+1 ; waves 2,3 -> rows 2b+4096,2b+4097.
// Waves 2,3 drop their float4s in LDS; waves 0,1 dot against registers =>
// pos partials at ZERO extra HBM traffic (gemm no longer reads o1/o2).
__global__ __launch_bounds__(256) void scatter_cast_kernel(const float* __restrict__ x,
                                                           const int* __restrict__ labels,
                                                           const int* __restrict__ wavebase,
                                                           _Float16* __restrict__ y,
                                                           float* __restrict__ loss) {
    __shared__ float4 xch[2][128];
    __shared__ float red[2];
    const int wv   = threadIdx.x >> 6;
    const int lane = threadIdx.x & 63;
    const int row  = blockIdx.x * 2 + (wv & 1) + ((wv >> 1) ? 4096 : 0);
    const int seg  = row >> 6;
    const int lab  = labels[seg * 64 + lane];    // label of segment-row `lane`
    unsigned long long m0 = __ballot(lab == 0), m1 = __ballot(lab == 1),
                       m2 = __ballot(lab == 2), m3 = __ballot(lab == 3),
                       m4 = __ballot(lab == 4), m5 = __ballot(lab == 5),
                       m6 = __ballot(lab == 6);
    unsigned long long mymask =
        lab == 0 ? m0 : lab == 1 ? m1 : lab == 2 ? m2 : lab == 3 ? m3 :
        lab == 4 ? m4 : lab == 5 ? m5 : m6;
    const unsigned long long lt = (1ull << lane) - 1ull;
    int dest_lane = wavebase[seg * NCLS + lab] + __builtin_popcountll(mymask & lt);
    int dest = __shfl(dest_lane, row & 63, 64);  // dest of THIS wave's row

    const float4* src = (const float4*)(x + (size_t)row * DIM);
    _Float16* dst = y + (size_t)dest * DIM;
    float4 v0 = src[lane];
    float4 v1 = src[lane + 64];

    if (wv >= 2) {                       // second view: publish for the pos dot
        xch[wv - 2][lane]      = v0;
        xch[wv - 2][lane + 64] = v1;
    }

    {   // cast + scatter store (all waves)
        f16x4 h;
        h[0] = (_Float16)v0.x; h[1] = (_Float16)v0.y;
        h[2] = (_Float16)v0.z; h[3] = (_Float16)v0.w;
        *(f16x4*)(dst + lane * 4) = h;
        h[0] = (_Float16)v1.x; h[1] = (_Float16)v1.y;
        h[2] = (_Float16)v1.z; h[3] = (_Float16)v1.w;
        *(f16x4*)(dst + (lane + 64) * 4) = h;
    }

    __syncthreads();
    if (wv < 2) {                        // first view: dot with paired row
        float4 b0 = xch[wv][lane];
        float4 b1 = xch[wv][lane + 64];
        float s = v0.x * b0.x + v0.y * b0.y + v0.z * b0.z + v0.w * b0.w
                + v1.x * b1.x + v1.y * b1.y + v1.z * b1.z + v1.w * b1.w;
        #pragma unroll
        for (int dd = 1; dd < 64; dd <<= 1) s += __shfl_xor(s, dd, 64);
        if (lane == 0) red[wv] = s;
    }
    __syncthreads();
    if (threadIdx.x == 0)
        atomicAdd(loss, -(red[0] + red[1]) * (1.0f / 2048.0f));
}

// ---------------- 3. GEMM over upper-triangle 64x64 class tiles ----------------
// 4 waves, each a 32x32 quadrant (acc 2x2 of f32x4). LDS fragment-ordered
// [2][4][64][8]; off-diag tiles emit row-sums AND col-sums (S^T reuse);
// diag tiles stage A only and mask i!=j.
__global__ __launch_bounds__(256, 6) void gemm_denom_kernel(const _Float16* __restrict__ X,
                                                            const int4* __restrict__ tiles,
                                                            const int* __restrict__ nTiles,
                                                            float* __restrict__ denom) {
    __shared__ __align__(16) _Float16 Atile[4096];  // [2][4][64][8] = 8 KiB
    __shared__ __align__(16) _Float16 Btile[4096];

    const int tid  = threadIdx.x;
    const int lane = tid & 63;
    const int wv   = tid >> 6;
    const int lc   = lane & 15;
    const int lq   = lane >> 4;
    const int l8   = lq * 8;
    const int nT   = nTiles[0];

    for (int t = blockIdx.x; t < nT; t += gridDim.x) {
        const int4 d = tiles[t];
        const int bm = d.x, bn = d.y, end = d.z;
        const bool diag = (bm == bn);

        f32x4 acc[2][2] = {};

        for (int kb = 0; kb < DIM; kb += 64) {
            __syncthreads();
            #pragma unroll
            for (int g = 0; g < 4; ++g) {
                int grp = wv + g * 4;             // 0..15, wave-uniform
                if (diag && grp >= 8) continue;   // diag: A tile only
                int idx = grp & 7;
                int kk2 = idx >> 2;
                int rg  = idx & 3;
                int row = (grp < 8 ? bm : bn) + rg * 16 + lc;
                row = min(row, end - 1);          // partial: dup last row, masked later
                int kcol = kb + kk2 * 32 + l8;
                const _Float16* src = X + (size_t)row * DIM + kcol;
                _Float16* dst = (grp < 8 ? Atile : Btile) + ((kk2 * 4 + rg) * 64 + lane) * 8;
                load16_g2l(dst, src);
            }
            __syncthreads();

            const _Float16* Bbase = diag ? Atile : Btile;
            const int rga = (wv >> 1) * 2;
            const int rgb = (wv & 1) * 2;
            #pragma unroll
            for (int kk2 = 0; kk2 < 2; ++kk2) {
                f16x8 af[2], bf[2];
                #pragma unroll
                for (int q = 0; q < 2; ++q)
                    af[q] = *(const f16x8*)&Atile[((kk2 * 4 + rga + q) * 64 + lane) * 8];
                #pragma unroll
                for (int q = 0; q < 2; ++q)
                    bf[q] = *(const f16x8*)&Bbase[((kk2 * 4 + rgb + q) * 64 + lane) * 8];
                #pragma unroll
                for (int mt = 0; mt < 2; ++mt)
                    #pragma unroll
                    for (int nt = 0; nt < 2; ++nt)
                        acc[mt][nt] = __builtin_amdgcn_mfma_f32_16x16x32_f16(
                            af[mt], bf[nt], acc[mt][nt], 0, 0, 0);
            }
        }

        // epilogue. C/D: col = lane&15, row = (lane>>4)*4 + reg   [m89/m91]
        const int row0 = bm + (wv >> 1) * 32;
        const int col0 = bn + (wv & 1) * 32;
        const float cs = 2.0f * 1.4426950408889634f;  // (1/T)*log2(e)

        float colsum[2] = {0.f, 0.f};
        #pragma unroll
        for (int mt = 0; mt < 2; ++mt) {
            #pragma unroll
            for (int r = 0; r < 4; ++r) {
                int grow = row0 + mt * 16 + lq * 4 + r;
                float s = 0.f;
                #pragma unroll
                for (int nt = 0; nt < 2; ++nt) {
                    int gcol = col0 + nt * 16 + lc;
                    float e = exp2f(acc[mt][nt][r] * cs);
                    bool ok = (gcol < end) && (!diag || (grow != gcol));
                    e = ok ? e : 0.f;
                    s += e;
                    colsum[nt] += e;
                }
                #pragma unroll
                for (int dd = 1; dd < 16; dd <<= 1) s += __shfl_xor(s, dd, 64);
                if (lc == 0 && grow < end) atomicAdd(&denom[grow], s);
            }
        }
        if (!diag) {  // mirrored tile's row-sums (row blocks of off-diag are always full)
            #pragma unroll
            for (int nt = 0; nt < 2; ++nt) {
                float c2 = colsum[nt];
                c2 += __shfl_xor(c2, 16, 64);
                c2 += __shfl_xor(c2, 32, 64);
                int gcol = col0 + nt * 16 + lc;
                if (lq == 0 && gcol < end) atomicAdd(&denom[gcol], c2);
            }
        }
    }
}

// ---------------- 4. mean(log(denom)) ----------------
__global__ __launch_bounds__(256) void logdenom_kernel(const float* __restrict__ denom,
                                                       float* __restrict__ out) {
    const int i = blockIdx.x * 256 + threadIdx.x;
    const float4* d4 = (const float4*)denom;
    float4 q = d4[i];
    float v = (__logf(q.x) + __logf(q.y) + __logf(q.z) + __logf(q.w)) * (1.0f / 8192.0f);
    #pragma unroll
    for (int d = 1; d < 64; d <<= 1) v += __shfl_xor(v, d, 64);
    __shared__ float red[4];
    if ((threadIdx.x & 63) == 0) red[threadIdx.x >> 6] = v;
    __syncthreads();
    if (threadIdx.x == 0) atomicAdd(out, red[0] + red[1] + red[2] + red[3]);
}

extern "C" void kernel_launch(void* const* d_in, const int* in_sizes, int n_in,
                              void* d_out, int out_size, void* d_ws, size_t ws_size,
                              hipStream_t stream) {
    const float* out_full = (const float*)d_in[0];  // [8192, 512]
    const int*   labels   = (const int*)d_in[3];    // [8192]
    float* loss = (float*)d_out;

    char* ws = (char*)d_ws;
    _Float16* Xs       = (_Float16*)ws;                    // 8 MiB
    float*    denomS   = (float*)(ws + 8388608);           // 32 KiB
    int*      wavebase = (int*)(ws + 8421376);             // 3.5 KiB
    int*      nTiles   = (int*)(ws + 8425472);             // 64 B
    int4*     tiles    = (int4*)(ws + 8425536);            // <=129 KiB (worst case)

    plan_kernel<<<1, 256, 0, stream>>>(labels, wavebase, tiles, nTiles, denomS, loss);
    scatter_cast_kernel<<<NROWS / 4, 256, 0, stream>>>(out_full, labels, wavebase, Xs, loss);

    gemm_denom_kernel<<<GEMM_GRID, 256, 0, stream>>>(Xs, tiles, nTiles, denomS);

    logdenom_kernel<<<NROWS / 1024, 256, 0, stream>>>(denomS, loss);
}

// Round 4
// 134.938 us; speedup vs baseline: 1.8904x; 1.0505x over previous
//
#include <hip/hip_runtime.h>
#include <stdint.h>

// SimCLR clear loss, MI355X — round 8: gemm tile 64->128.
//  - Staged panel traffic scales as 1/Btile: 170 MB -> 96 MB; barrier-drain
//    events 10.6k -> 3.1k. One structural change for clean attribution.
//  - gemm: 512 thr / 8 waves, each wave a 64x32 quadrant (acc 4x2 of f32x4),
//    LDS fragment-ordered [2][8][64][8] per panel (16 KiB), 2-barrier K-loop,
//    global_load_lds staging, row+col sum epilogue (S^T reuse), diag masked.
//  - plan emits 128-row tiles; scatter+pos and logdenom unchanged (round 7).

#define NROWS 8192
#define DIM   512
#define NCLS  7
#define GEMM_GRID 512

typedef _Float16 f16x8 __attribute__((ext_vector_type(8)));
typedef _Float16 f16x4 __attribute__((ext_vector_type(4)));
typedef float    f32x4 __attribute__((ext_vector_type(4)));

__device__ __forceinline__ void load16_g2l(void* lds, const void* g) {
    auto* l3 = reinterpret_cast<__attribute__((address_space(3))) uint32_t*>(
        reinterpret_cast<uintptr_t>(lds));
    auto* g1 = reinterpret_cast<const __attribute__((address_space(1))) uint32_t*>(
        reinterpret_cast<uintptr_t>(g));
    __builtin_amdgcn_global_load_lds(g1, l3, 16, 0, 0);
}

// ---------------- 1. planner ----------------
__global__ __launch_bounds__(256) void plan_kernel(const int* __restrict__ labels,
                                                   int* __restrict__ wavebase,
                                                   int4* __restrict__ tiles,
                                                   int* __restrict__ nTiles,
                                                   float* __restrict__ denomS,
                                                   float* __restrict__ loss) {
    __shared__ int cnt[128][NCLS];
    __shared__ int pref[128][NCLS];
    __shared__ int hist[NCLS];
    __shared__ int off[NCLS + 1];
    __shared__ int tb[NCLS + 1];
    const int tid = threadIdx.x;

    if (tid < 128) {
        int c0 = 0, c1 = 0, c2 = 0, c3 = 0, c4 = 0, c5 = 0, c6 = 0;
        const int4* l4 = (const int4*)labels + tid * 16;   // 64 labels = 16 int4
        #pragma unroll 4
        for (int j = 0; j < 16; ++j) {
            int4 v = l4[j];
            c0 += (v.x == 0) + (v.y == 0) + (v.z == 0) + (v.w == 0);
            c1 += (v.x == 1) + (v.y == 1) + (v.z == 1) + (v.w == 1);
            c2 += (v.x == 2) + (v.y == 2) + (v.z == 2) + (v.w == 2);
            c3 += (v.x == 3) + (v.y == 3) + (v.z == 3) + (v.w == 3);
            c4 += (v.x == 4) + (v.y == 4) + (v.z == 4) + (v.w == 4);
            c5 += (v.x == 5) + (v.y == 5) + (v.z == 5) + (v.w == 5);
            c6 += (v.x == 6) + (v.y == 6) + (v.z == 6) + (v.w == 6);
        }
        cnt[tid][0] = c0; cnt[tid][1] = c1; cnt[tid][2] = c2; cnt[tid][3] = c3;
        cnt[tid][4] = c4; cnt[tid][5] = c5; cnt[tid][6] = c6;
    }
    __syncthreads();
    if (tid < NCLS) {
        int run = 0;
        for (int s = 0; s < 128; ++s) { pref[s][tid] = run; run += cnt[s][tid]; }
        hist[tid] = run;
    }
    __syncthreads();
    if (tid == 0) {
        int o = 0, t = 0;
        for (int c = 0; c < NCLS; ++c) {
            off[c] = o; tb[c] = t;
            int T = (hist[c] + 127) >> 7;          // 128-row panels
            o += hist[c]; t += T * (T + 1) / 2;
        }
        off[NCLS] = o; tb[NCLS] = t;
        nTiles[0] = t;
        *loss = 0.f;
    }
    __syncthreads();
    for (int i = tid; i < 128 * NCLS; i += 256) {
        int s = i / NCLS, c = i - s * NCLS;
        wavebase[i] = off[c] + pref[s][c];
    }
    const int tot = tb[NCLS];
    for (int t = tid; t < tot; t += 256) {
        int c = 0;
        while (t >= tb[c + 1]) ++c;
        int rem = t - tb[c];
        int T = (hist[c] + 127) >> 7;
        int ti = 0;
        while (rem >= T - ti) { rem -= (T - ti); ++ti; }   // ti<=tj
        int tj = ti + rem;
        tiles[t] = make_int4(off[c] + ti * 128, off[c] + tj * 128, off[c] + hist[c], 0);
    }
    for (int i = tid; i < NROWS; i += 256) denomS[i] = 0.f;
}

// ---------------- 2. fused scatter + cast + pos dot (atomic-free scatter) ----------------
// Block b (of 2048): waves 0,1 -> rows 2b,2b+1 ; waves 2,3 -> rows 2b+4096,2b+4097.
// Waves 2,3 drop their float4s in LDS; waves 0,1 dot against registers =>
// pos partials at ZERO extra HBM traffic (gemm does not read o1/o2).
__global__ __launch_bounds__(256) void scatter_cast_kernel(const float* __restrict__ x,
                                                           const int* __restrict__ labels,
                                                           const int* __restrict__ wavebase,
                                                           _Float16* __restrict__ y,
                                                           float* __restrict__ loss) {
    __shared__ float4 xch[2][128];
    __shared__ float red[2];
    const int wv   = threadIdx.x >> 6;
    const int lane = threadIdx.x & 63;
    const int row  = blockIdx.x * 2 + (wv & 1) + ((wv >> 1) ? 4096 : 0);
    const int seg  = row >> 6;
    const int lab  = labels[seg * 64 + lane];    // label of segment-row `lane`
    unsigned long long m0 = __ballot(lab == 0), m1 = __ballot(lab == 1),
                       m2 = __ballot(lab == 2), m3 = __ballot(lab == 3),
                       m4 = __ballot(lab == 4), m5 = __ballot(lab == 5),
                       m6 = __ballot(lab == 6);
    unsigned long long mymask =
        lab == 0 ? m0 : lab == 1 ? m1 : lab == 2 ? m2 : lab == 3 ? m3 :
        lab == 4 ? m4 : lab == 5 ? m5 : m6;
    const unsigned long long lt = (1ull << lane) - 1ull;
    int dest_lane = wavebase[seg * NCLS + lab] + __builtin_popcountll(mymask & lt);
    int dest = __shfl(dest_lane, row & 63, 64);  // dest of THIS wave's row

    const float4* src = (const float4*)(x + (size_t)row * DIM);
    _Float16* dst = y + (size_t)dest * DIM;
    float4 v0 = src[lane];
    float4 v1 = src[lane + 64];

    if (wv >= 2) {                       // second view: publish for the pos dot
        xch[wv - 2][lane]      = v0;
        xch[wv - 2][lane + 64] = v1;
    }

    {   // cast + scatter store (all waves)
        f16x4 h;
        h[0] = (_Float16)v0.x; h[1] = (_Float16)v0.y;
        h[2] = (_Float16)v0.z; h[3] = (_Float16)v0.w;
        *(f16x4*)(dst + lane * 4) = h;
        h[0] = (_Float16)v1.x; h[1] = (_Float16)v1.y;
        h[2] = (_Float16)v1.z; h[3] = (_Float16)v1.w;
        *(f16x4*)(dst + (lane + 64) * 4) = h;
    }

    __syncthreads();
    if (wv < 2) {                        // first view: dot with paired row
        float4 b0 = xch[wv][lane];
        float4 b1 = xch[wv][lane + 64];
        float s = v0.x * b0.x + v0.y * b0.y + v0.z * b0.z + v0.w * b0.w
                + v1.x * b1.x + v1.y * b1.y + v1.z * b1.z + v1.w * b1.w;
        #pragma unroll
        for (int dd = 1; dd < 64; dd <<= 1) s += __shfl_xor(s, dd, 64);
        if (lane == 0) red[wv] = s;
    }
    __syncthreads();
    if (threadIdx.x == 0)
        atomicAdd(loss, -(red[0] + red[1]) * (1.0f / 2048.0f));
}

// ---------------- 3. GEMM over upper-triangle 128x128 class tiles ----------------
// 8 waves, each a 64x32 quadrant (wr = wv>>2 row-half, wc = wv&3 col-quarter;
// acc 4x2 of f32x4). LDS fragment-ordered [2][8][64][8] per panel; off-diag
// tiles emit row-sums AND col-sums (S^T reuse); diag tiles stage A only and
// mask i!=j; partial panels: staging row-clamped, epilogue masked.
__global__ __launch_bounds__(512) void gemm_denom_kernel(const _Float16* __restrict__ X,
                                                         const int4* __restrict__ tiles,
                                                         const int* __restrict__ nTiles,
                                                         float* __restrict__ denom) {
    __shared__ __align__(16) _Float16 Atile[8192];  // [2][8][64][8] = 16 KiB
    __shared__ __align__(16) _Float16 Btile[8192];

    const int tid  = threadIdx.x;
    const int lane = tid & 63;
    const int wv   = tid >> 6;       // 0..7
    const int lc   = lane & 15;
    const int lq   = lane >> 4;
    const int l8   = lq * 8;
    const int wr   = wv >> 2;        // 0..1 : 64-row half
    const int wc   = wv & 3;         // 0..3 : 32-col quarter
    const int nT   = nTiles[0];

    for (int t = blockIdx.x; t < nT; t += gridDim.x) {
        const int4 d = tiles[t];
        const int bm = d.x, bn = d.y, end = d.z;
        const bool diag = (bm == bn);

        f32x4 acc[4][2] = {};

        for (int kb = 0; kb < DIM; kb += 64) {
            __syncthreads();
            #pragma unroll
            for (int g = 0; g < 4; ++g) {
                int grp = wv + g * 8;             // 0..31, wave-uniform
                if (diag && grp >= 16) continue;  // diag: A tile only
                int idx = grp & 15;
                int kk2 = idx >> 3;
                int rg  = idx & 7;
                int row = (grp < 16 ? bm : bn) + rg * 16 + lc;
                row = min(row, end - 1);          // partial: dup last row, masked later
                int kcol = kb + kk2 * 32 + l8;
                const _Float16* src = X + (size_t)row * DIM + kcol;
                _Float16* dst = (grp < 16 ? Atile : Btile) + ((kk2 * 8 + rg) * 64 + lane) * 8;
                load16_g2l(dst, src);
            }
            __syncthreads();

            const _Float16* Bbase = diag ? Atile : Btile;
            #pragma unroll
            for (int kk2 = 0; kk2 < 2; ++kk2) {
                f16x8 af[4], bf[2];
                #pragma unroll
                for (int q = 0; q < 4; ++q)
                    af[q] = *(const f16x8*)&Atile[((kk2 * 8 + wr * 4 + q) * 64 + lane) * 8];
                #pragma unroll
                for (int q = 0; q < 2; ++q)
                    bf[q] = *(const f16x8*)&Bbase[((kk2 * 8 + wc * 2 + q) * 64 + lane) * 8];
                #pragma unroll
                for (int mt = 0; mt < 4; ++mt)
                    #pragma unroll
                    for (int nt = 0; nt < 2; ++nt)
                        acc[mt][nt] = __builtin_amdgcn_mfma_f32_16x16x32_f16(
                            af[mt], bf[nt], acc[mt][nt], 0, 0, 0);
            }
        }

        // epilogue. C/D: col = lane&15, row = (lane>>4)*4 + reg   [m89/m91]
        const int row0 = bm + wr * 64;
        const int col0 = bn + wc * 32;
        const float cs = 2.0f * 1.4426950408889634f;  // (1/T)*log2(e)

        float colsum[2] = {0.f, 0.f};
        #pragma unroll
        for (int mt = 0; mt < 4; ++mt) {
            #pragma unroll
            for (int r = 0; r < 4; ++r) {
                int grow = row0 + mt * 16 + lq * 4 + r;
                float s = 0.f;
                #pragma unroll
                for (int nt = 0; nt < 2; ++nt) {
                    int gcol = col0 + nt * 16 + lc;
                    float e = exp2f(acc[mt][nt][r] * cs);
                    bool ok = (gcol < end) && (!diag || (grow != gcol));
                    e = ok ? e : 0.f;
                    s += e;
                    colsum[nt] += e;
                }
                #pragma unroll
                for (int dd = 1; dd < 16; dd <<= 1) s += __shfl_xor(s, dd, 64);
                if (lc == 0 && grow < end) atomicAdd(&denom[grow], s);
            }
        }
        if (!diag) {  // mirrored tile's row-sums (row panels of off-diag are always full)
            #pragma unroll
            for (int nt = 0; nt < 2; ++nt) {
                float c2 = colsum[nt];
                c2 += __shfl_xor(c2, 16, 64);
                c2 += __shfl_xor(c2, 32, 64);
                int gcol = col0 + nt * 16 + lc;
                if (lq == 0 && gcol < end) atomicAdd(&denom[gcol], c2);
            }
        }
    }
}

// ---------------- 4. mean(log(denom)) ----------------
__global__ __launch_bounds__(256) void logdenom_kernel(const float* __restrict__ denom,
                                                       float* __restrict__ out) {
    const int i = blockIdx.x * 256 + threadIdx.x;
    const float4* d4 = (const float4*)denom;
    float4 q = d4[i];
    float v = (__logf(q.x) + __logf(q.y) + __logf(q.z) + __logf(q.w)) * (1.0f / 8192.0f);
    #pragma unroll
    for (int d = 1; d < 64; d <<= 1) v += __shfl_xor(v, d, 64);
    __shared__ float red[4];
    if ((threadIdx.x & 63) == 0) red[threadIdx.x >> 6] = v;
    __syncthreads();
    if (threadIdx.x == 0) atomicAdd(out, red[0] + red[1] + red[2] + red[3]);
}

extern "C" void kernel_launch(void* const* d_in, const int* in_sizes, int n_in,
                              void* d_out, int out_size, void* d_ws, size_t ws_size,
                              hipStream_t stream) {
    const float* out_full = (const float*)d_in[0];  // [8192, 512]
    const int*   labels   = (const int*)d_in[3];    // [8192]
    float* loss = (float*)d_out;

    char* ws = (char*)d_ws;
    _Float16* Xs       = (_Float16*)ws;                    // 8 MiB
    float*    denomS   = (float*)(ws + 8388608);           // 32 KiB
    int*      wavebase = (int*)(ws + 8421376);             // 3.5 KiB
    int*      nTiles   = (int*)(ws + 8425472);             // 64 B
    int4*     tiles    = (int4*)(ws + 8425536);            // <=33 KiB worst case (T=64)

    plan_kernel<<<1, 256, 0, stream>>>(labels, wavebase, tiles, nTiles, denomS, loss);
    scatter_cast_kernel<<<NROWS / 4, 256, 0, stream>>>(out_full, labels, wavebase, Xs, loss);

    gemm_denom_kernel<<<GEMM_GRID, 512, 0, stream>>>(Xs, tiles, nTiles, denomS);

    logdenom_kernel<<<NROWS / 1024, 256, 0, stream>>>(denomS, loss);
}

// Round 9
// 110.928 us; speedup vs baseline: 2.2996x; 1.2164x over previous
//
#include <hip/hip_runtime.h>
#include <stdint.h>

// SimCLR clear loss, MI355X — round 13 (= round 9..12 resubmitted verbatim;
// four consecutive acquisition timeouts, kernel has never run. Audited twice.)
//  - plan_kernel removed. Its products are recomputed redundantly where needed:
//    * scatter blocks (512 x 16 rows) rebuild per-segment class counts from all
//      8192 labels in LDS and derive wavebase via packed shuffle prefix.
//    * gemm blocks build the 7-bin class histogram (shuffle reduce) and derive
//      the triangular 128x128 tile list arithmetically — no tile table.
//  - scatter zeros denom slices + writes pos partials to posPart[] (no atomics,
//    no loss-init ordering). finalize = 1 block, plain store.
//  - chain: 4 launches -> 3; head-of-chain 1-block latency gone.

#define NROWS 8192
#define DIM   512
#define NCLS  7
#define GEMM_GRID 512

typedef _Float16 f16x8 __attribute__((ext_vector_type(8)));
typedef _Float16 f16x4 __attribute__((ext_vector_type(4)));
typedef float    f32x4 __attribute__((ext_vector_type(4)));

__device__ __forceinline__ void load16_g2l(void* lds, const void* g) {
    auto* l3 = reinterpret_cast<__attribute__((address_space(3))) uint32_t*>(
        reinterpret_cast<uintptr_t>(lds));
    auto* g1 = reinterpret_cast<const __attribute__((address_space(1))) uint32_t*>(
        reinterpret_cast<uintptr_t>(g));
    __builtin_amdgcn_global_load_lds(g1, l3, 16, 0, 0);
}

// ---------------- 1. fused plan + scatter + cast + pos dot ----------------
// Block b (of 512): first-view rows 8b..8b+7 (waves 0,1: 4 each),
// second-view rows +4096 (waves 2,3). All rows of a wave share one segment.
// Per-block redundant plan: 8192 labels -> cnt[128][7] in LDS -> packed
// (prefix|full<<16) shuffle reduction gives this wave's wavebase[7].
__global__ __launch_bounds__(256) void scatter_plan_kernel(const float* __restrict__ x,
                                                           const int* __restrict__ labels,
                                                           _Float16* __restrict__ y,
                                                           float* __restrict__ denomS,
                                                           float* __restrict__ posPart) {
    __shared__ int    halfc[256][8];     // per-half-segment class counts
    __shared__ int    cnt[128][8];       // per-segment class counts
    __shared__ float4 xch[8][128];       // second-view rows for pos dot
    __shared__ float  red[2];
    const int tid  = threadIdx.x;
    const int lane = tid & 63;
    const int wv   = tid >> 6;
    const int b    = blockIdx.x;

    {   // count 32 labels (= half of segment tid>>1)
        const int4* l4 = (const int4*)labels + tid * 8;
        int c0 = 0, c1 = 0, c2 = 0, c3 = 0, c4 = 0, c5 = 0, c6 = 0;
        #pragma unroll
        for (int j = 0; j < 8; ++j) {
            int4 v = l4[j];
            c0 += (v.x == 0) + (v.y == 0) + (v.z == 0) + (v.w == 0);
            c1 += (v.x == 1) + (v.y == 1) + (v.z == 1) + (v.w == 1);
            c2 += (v.x == 2) + (v.y == 2) + (v.z == 2) + (v.w == 2);
            c3 += (v.x == 3) + (v.y == 3) + (v.z == 3) + (v.w == 3);
            c4 += (v.x == 4) + (v.y == 4) + (v.z == 4) + (v.w == 4);
            c5 += (v.x == 5) + (v.y == 5) + (v.z == 5) + (v.w == 5);
            c6 += (v.x == 6) + (v.y == 6) + (v.z == 6) + (v.w == 6);
        }
        halfc[tid][0] = c0; halfc[tid][1] = c1; halfc[tid][2] = c2;
        halfc[tid][3] = c3; halfc[tid][4] = c4; halfc[tid][5] = c5;
        halfc[tid][6] = c6;
    }
    __syncthreads();
    if (tid < 128) {
        #pragma unroll
        for (int c = 0; c < NCLS; ++c)
            cnt[tid][c] = halfc[2 * tid][c] + halfc[2 * tid + 1][c];
    }
    __syncthreads();

    // wave's segment: waves 0,1 -> b>>3 ; waves 2,3 -> b>>3 + 64
    const int s = (b >> 3) + (wv >> 1) * 64;

    // wavebase[c] = class_offset(c) + sum_{s'<s} cnt[s'][c], via packed reduce
    int wb[NCLS];
    {
        int o = 0;
        #pragma unroll
        for (int c = 0; c < NCLS; ++c) {
            int a0 = cnt[lane][c], a1 = cnt[lane + 64][c];
            int p = (lane < s ? a0 : 0) + (lane + 64 < s ? a1 : 0);
            int packed = p | ((a0 + a1) << 16);
            #pragma unroll
            for (int dd = 1; dd < 64; dd <<= 1) packed += __shfl_xor(packed, dd, 64);
            wb[c] = o + (packed & 0xffff);
            o += (packed >> 16);
        }
    }

    // ballot rank within segment
    const int lab = labels[s * 64 + lane];
    unsigned long long m0 = __ballot(lab == 0), m1 = __ballot(lab == 1),
                       m2 = __ballot(lab == 2), m3 = __ballot(lab == 3),
                       m4 = __ballot(lab == 4), m5 = __ballot(lab == 5),
                       m6 = __ballot(lab == 6);
    unsigned long long mymask =
        lab == 0 ? m0 : lab == 1 ? m1 : lab == 2 ? m2 : lab == 3 ? m3 :
        lab == 4 ? m4 : lab == 5 ? m5 : m6;
    int wbsel = lab == 0 ? wb[0] : lab == 1 ? wb[1] : lab == 2 ? wb[2] :
                lab == 3 ? wb[3] : lab == 4 ? wb[4] : lab == 5 ? wb[5] : wb[6];
    const unsigned long long lt = (1ull << lane) - 1ull;
    const int dest_lane = wbsel + __builtin_popcountll(mymask & lt);

    // load 4 rows (lane covers contiguous 8 floats: float4 pair 2*lane, 2*lane+1)
    const int r0 = b * 8 + (wv & 1) * 4 + (wv >> 1) * 4096;
    float4 va[8];
    #pragma unroll
    for (int j = 0; j < 4; ++j) {
        const float4* src = (const float4*)(x + (size_t)(r0 + j) * DIM);
        va[2 * j]     = src[2 * lane];
        va[2 * j + 1] = src[2 * lane + 1];
    }
    if (wv >= 2) {      // publish second view for the pos dot
        #pragma unroll
        for (int j = 0; j < 4; ++j) {
            xch[(wv - 2) * 4 + j][2 * lane]     = va[2 * j];
            xch[(wv - 2) * 4 + j][2 * lane + 1] = va[2 * j + 1];
        }
    }

    // cast + scatter store: one 16B f16x8 per row per lane
    #pragma unroll
    for (int j = 0; j < 4; ++j) {
        int dest = __shfl(dest_lane, (r0 + j) & 63, 64);
        f16x8 h;
        h[0] = (_Float16)va[2 * j].x;     h[1] = (_Float16)va[2 * j].y;
        h[2] = (_Float16)va[2 * j].z;     h[3] = (_Float16)va[2 * j].w;
        h[4] = (_Float16)va[2 * j + 1].x; h[5] = (_Float16)va[2 * j + 1].y;
        h[6] = (_Float16)va[2 * j + 1].z; h[7] = (_Float16)va[2 * j + 1].w;
        *(f16x8*)(y + (size_t)dest * DIM + lane * 8) = h;
    }

    __syncthreads();
    if (wv < 2) {       // first view: dot against paired second-view rows
        float acc = 0.f;
        #pragma unroll
        for (int j = 0; j < 4; ++j) {
            float4 b0 = xch[wv * 4 + j][2 * lane];
            float4 b1 = xch[wv * 4 + j][2 * lane + 1];
            acc += va[2 * j].x * b0.x + va[2 * j].y * b0.y
                 + va[2 * j].z * b0.z + va[2 * j].w * b0.w
                 + va[2 * j + 1].x * b1.x + va[2 * j + 1].y * b1.y
                 + va[2 * j + 1].z * b1.z + va[2 * j + 1].w * b1.w;
        }
        #pragma unroll
        for (int dd = 1; dd < 64; dd <<= 1) acc += __shfl_xor(acc, dd, 64);
        if (lane == 0) red[wv] = acc;
    }
    __syncthreads();
    if (tid == 0) posPart[b] = red[0] + red[1];
    if (tid < 4) ((float4*)denomS)[b * 4 + tid] = make_float4(0.f, 0.f, 0.f, 0.f);
}

// ---------------- 2. GEMM over upper-triangle 128x128 class tiles ----------------
// Tile list derived on the fly from a per-block 7-bin label histogram.
// 8 waves, each a 64x32 quadrant (acc 4x2 of f32x4); LDS fragment-ordered
// [2][8][64][8]; off-diag tiles emit row+col sums (S^T reuse); diag masks i!=j.
__global__ __launch_bounds__(512) void gemm_denom_kernel(const _Float16* __restrict__ X,
                                                         const int* __restrict__ labels,
                                                         float* __restrict__ denom) {
    __shared__ __align__(16) _Float16 Atile[8192];  // [2][8][64][8] = 16 KiB
    __shared__ __align__(16) _Float16 Btile[8192];
    __shared__ int whist[8][8];
    __shared__ int s_hist[8], s_off[8], s_tb[8];

    const int tid  = threadIdx.x;
    const int lane = tid & 63;
    const int wv   = tid >> 6;       // 0..7
    const int lc   = lane & 15;
    const int lq   = lane >> 4;
    const int l8   = lq * 8;
    const int wr   = wv >> 2;        // 0..1 : 64-row half
    const int wc   = wv & 3;         // 0..3 : 32-col quarter

    {   // class histogram: 512 threads x 16 labels, wave shuffle reduce
        const int4* l4 = (const int4*)labels + tid * 4;
        int cc[NCLS];
        #pragma unroll
        for (int c = 0; c < NCLS; ++c) cc[c] = 0;
        #pragma unroll
        for (int j = 0; j < 4; ++j) {
            int4 v = l4[j];
            #pragma unroll
            for (int c = 0; c < NCLS; ++c)
                cc[c] += (v.x == c) + (v.y == c) + (v.z == c) + (v.w == c);
        }
        #pragma unroll
        for (int c = 0; c < NCLS; ++c) {
            int t = cc[c];
            #pragma unroll
            for (int dd = 1; dd < 64; dd <<= 1) t += __shfl_xor(t, dd, 64);
            if (lane == 0) whist[wv][c] = t;
        }
    }
    __syncthreads();
    if (tid == 0) {
        int o = 0, tb = 0;
        #pragma unroll
        for (int c = 0; c < NCLS; ++c) {
            int h = 0;
            #pragma unroll
            for (int w = 0; w < 8; ++w) h += whist[w][c];
            int T = (h + 127) >> 7;
            s_hist[c] = h; s_off[c] = o; s_tb[c] = tb;
            o += h; tb += T * (T + 1) / 2;
        }
        s_tb[NCLS] = tb;
    }
    __syncthreads();
    const int nT = s_tb[NCLS];

    for (int t = blockIdx.x; t < nT; t += gridDim.x) {
        int c = 0;
        while (t >= s_tb[c + 1]) ++c;
        int rem = t - s_tb[c];
        int T = (s_hist[c] + 127) >> 7;
        int ti = 0;
        while (rem >= T - ti) { rem -= (T - ti); ++ti; }   // ti<=tj
        const int tj  = ti + rem;
        const int bm  = s_off[c] + ti * 128;
        const int bn  = s_off[c] + tj * 128;
        const int end = s_off[c] + s_hist[c];
        const bool diag = (bm == bn);

        f32x4 acc[4][2] = {};

        for (int kb = 0; kb < DIM; kb += 64) {
            __syncthreads();
            #pragma unroll
            for (int g = 0; g < 4; ++g) {
                int grp = wv + g * 8;             // 0..31, wave-uniform
                if (diag && grp >= 16) continue;  // diag: A tile only
                int idx = grp & 15;
                int kk2 = idx >> 3;
                int rg  = idx & 7;
                int row = (grp < 16 ? bm : bn) + rg * 16 + lc;
                row = min(row, end - 1);          // partial: dup last row, masked later
                int kcol = kb + kk2 * 32 + l8;
                const _Float16* src = X + (size_t)row * DIM + kcol;
                _Float16* dst = (grp < 16 ? Atile : Btile) + ((kk2 * 8 + rg) * 64 + lane) * 8;
                load16_g2l(dst, src);
            }
            __syncthreads();

            const _Float16* Bbase = diag ? Atile : Btile;
            #pragma unroll
            for (int kk2 = 0; kk2 < 2; ++kk2) {
                f16x8 af[4], bf[2];
                #pragma unroll
                for (int q = 0; q < 4; ++q)
                    af[q] = *(const f16x8*)&Atile[((kk2 * 8 + wr * 4 + q) * 64 + lane) * 8];
                #pragma unroll
                for (int q = 0; q < 2; ++q)
                    bf[q] = *(const f16x8*)&Bbase[((kk2 * 8 + wc * 2 + q) * 64 + lane) * 8];
                #pragma unroll
                for (int mt = 0; mt < 4; ++mt)
                    #pragma unroll
                    for (int nt = 0; nt < 2; ++nt)
                        acc[mt][nt] = __builtin_amdgcn_mfma_f32_16x16x32_f16(
                            af[mt], bf[nt], acc[mt][nt], 0, 0, 0);
            }
        }

        // epilogue. C/D: col = lane&15, row = (lane>>4)*4 + reg   [m89/m91]
        const int row0 = bm + wr * 64;
        const int col0 = bn + wc * 32;
        const float cs = 2.0f * 1.4426950408889634f;  // (1/T)*log2(e)

        float colsum[2] = {0.f, 0.f};
        #pragma unroll
        for (int mt = 0; mt < 4; ++mt) {
            #pragma unroll
            for (int r = 0; r < 4; ++r) {
                int grow = row0 + mt * 16 + lq * 4 + r;
                float s = 0.f;
                #pragma unroll
                for (int nt = 0; nt < 2; ++nt) {
                    int gcol = col0 + nt * 16 + lc;
                    float e = exp2f(acc[mt][nt][r] * cs);
                    bool ok = (gcol < end) && (!diag || (grow != gcol));
                    e = ok ? e : 0.f;
                    s += e;
                    colsum[nt] += e;
                }
                #pragma unroll
                for (int dd = 1; dd < 16; dd <<= 1) s += __shfl_xor(s, dd, 64);
                if (lc == 0 && grow < end) atomicAdd(&denom[grow], s);
            }
        }
        if (!diag) {  // mirrored tile's row-sums (row panels of off-diag are always full)
            #pragma unroll
            for (int nt = 0; nt < 2; ++nt) {
                float c2 = colsum[nt];
                c2 += __shfl_xor(c2, 16, 64);
                c2 += __shfl_xor(c2, 32, 64);
                int gcol = col0 + nt * 16 + lc;
                if (lq == 0 && gcol < end) atomicAdd(&denom[gcol], c2);
            }
        }
    }
}

// ---------------- 3. finalize: loss = mean(log denom) - sum(pos)/2048 ----------------
__global__ __launch_bounds__(256) void finalize_kernel(const float* __restrict__ denom,
                                                       const float* __restrict__ posPart,
                                                       float* __restrict__ loss) {
    const int tid = threadIdx.x;
    float v = 0.f;
    const float4* d4 = (const float4*)denom;
    #pragma unroll
    for (int i = 0; i < 8; ++i) {
        float4 q = d4[tid + i * 256];
        v += (__logf(q.x) + __logf(q.y) + __logf(q.z) + __logf(q.w)) * (1.0f / 8192.0f);
    }
    const float4* p4 = (const float4*)posPart;   // 512 floats = 128 float4
    if (tid < 128) {
        float4 q = p4[tid];
        v -= (q.x + q.y + q.z + q.w) * (1.0f / 2048.0f);
    }
    #pragma unroll
    for (int dd = 1; dd < 64; dd <<= 1) v += __shfl_xor(v, dd, 64);
    __shared__ float red[4];
    if ((tid & 63) == 0) red[tid >> 6] = v;
    __syncthreads();
    if (tid == 0) loss[0] = red[0] + red[1] + red[2] + red[3];
}

extern "C" void kernel_launch(void* const* d_in, const int* in_sizes, int n_in,
                              void* d_out, int out_size, void* d_ws, size_t ws_size,
                              hipStream_t stream) {
    const float* out_full = (const float*)d_in[0];  // [8192, 512]
    const int*   labels   = (const int*)d_in[3];    // [8192]
    float* loss = (float*)d_out;

    char* ws = (char*)d_ws;
    _Float16* Xs      = (_Float16*)ws;                 // 8 MiB
    float*    denomS  = (float*)(ws + 8388608);        // 32 KiB
    float*    posPart = (float*)(ws + 8421376);        // 2 KiB

    scatter_plan_kernel<<<512, 256, 0, stream>>>(out_full, labels, Xs, denomS, posPart);
    gemm_denom_kernel<<<GEMM_GRID, 512, 0, stream>>>(Xs, labels, denomS);
    finalize_kernel<<<1, 256, 0, stream>>>(denomS, posPart, loss);
}